// Round 11
// baseline (134.450 us; speedup 1.0000x reference)
//
#include <hip/hip_runtime.h>

// x (B,I); w/s/t (O,I); out (B,O), all fp32.
#define B_SZ 256
#define O_SZ 1024
#define I_SZ 1024

#define TB   8     // b rows per block (LDS x tile)
#define SLN  32    // lanes per half splitting i
#define KITERS (I_SZ / (SLN * 4))   // 8
#define ISTEP  (SLN * 4)            // 128
#define OITER  4                    // o-groups per block (32 o's/block)

typedef float v2f __attribute__((ext_vector_type(2)));

// out[b,o] = sum_i w[o,i]*phi((x[b,i]-t[o,i])/s[o,i]),  phi(z) = -z*exp(-0.5 z^2)
//
// R10 post-mortem: v_exp_f32 (quarter-rate trans, ~16 cyc/wave) was 65k of 80k busy
// cyc/SIMD and the duty cycle pinned at ~61%. This round removes the trans pipe:
// exp(-v/2) on v=z^2 in [0,12] via degree-6 Chebyshev (xi = v/6-1, coeffs from
// e^-3 * Bessel-I expansion of exp(-3 xi); max abs err 5.4e-4; v clamped to 12 --
// beyond, |phi|<0.012*|w| on ~0.05% of terms). All math is full-rate v_pk_*_f32:
// 12 pk ops per element-pair vs 4 pk + 2 exp before. Error budget: threshold 1.31,
// accumulated poly error ~0.005 on top of existing 0.125 fp32 noise.
//
// Structure = R10 (proven no-spill 44-VGPR regime): LDS x tile reused across 4
// o-groups, 1024 blocks = 4/CU, w/s/t register-prefetched one k-iter ahead.
__launch_bounds__(256, 4)
__global__ void wavkan_dog_kernel(const float* __restrict__ X,
                                  const float* __restrict__ W,
                                  const float* __restrict__ S,
                                  const float* __restrict__ T,
                                  float* __restrict__ Out) {
    const int tid  = threadIdx.x;
    const int wave = tid >> 6;
    const int lane = tid & 63;
    const int half = lane >> 5;
    const int sl   = lane & (SLN - 1);

    const int obase = blockIdx.x * (8 * OITER) + wave * 2 + half; // + oi*8
    const int b0    = blockIdx.y * TB;

    __shared__ __align__(16) float xls[TB * I_SZ];     // 32 KB

    const int r0 = obase * I_SZ + sl * 4;
    const float* wr = W + r0;
    const float* sr = S + r0;
    const float* tr = T + r0;

    // first w/s/t prefetch issued before the LDS fill (flies under the barrier)
    float4 sN = *(const float4*)(sr);
    float4 tN = *(const float4*)(tr);
    float4 wN = *(const float4*)(wr);

    {   // cooperative fill: x[b0:b0+8][:] is one contiguous 32 KB span
        const float4* Xg4 = (const float4*)(X + (size_t)b0 * I_SZ);
        float4* L4 = (float4*)xls;
#pragma unroll
        for (int p = 0; p < (TB * I_SZ / 4) / 256; ++p)
            L4[tid + p * 256] = Xg4[tid + p * 256];
    }
    __syncthreads();

    // exp(-v/2) ~= Horner in xi = v/6 - 1, v in [0,12]  (abs err <= 5.4e-4)
    const float D0 = 0.0497068f,  D1 = -0.1523502f, D2 = 0.2265553f,
                D3 = -0.2006810f, D4 = 0.1557838f,  D5 = -0.1452684f,
                D6 = 0.0691109f;
    const float* xb = xls + sl * 4;

#pragma unroll 1
    for (int oi = 0; oi < OITER; ++oi) {
        const int ob = oi * 8 * I_SZ;

        v2f acc[TB];
#pragma unroll
        for (int j = 0; j < TB; ++j) acc[j] = (v2f)(0.0f);

#pragma unroll 2
        for (int k = 0; k < KITERS; ++k) {
            const int i = k * ISTEP;
            const int in = (k < KITERS - 1) ? (ob + (k + 1) * ISTEP)
                                            : ((((oi + 1) & (OITER - 1)) * 8) * I_SZ);

            const float4 s4 = sN, t4 = tN, w4 = wN;
            sN = *(const float4*)(sr + in);     // prefetch next k (or next o-group)
            tN = *(const float4*)(tr + in);
            wN = *(const float4*)(wr + in);

            v2f rk[2], tkn[2], wk[2];
            {
                const float* sa = (const float*)&s4;
                const float* ta = (const float*)&t4;
                const float* wa = (const float*)&w4;
#pragma unroll
                for (int cp = 0; cp < 2; ++cp) {
                    const v2f r = { __builtin_amdgcn_rcpf(sa[2*cp]),
                                    __builtin_amdgcn_rcpf(sa[2*cp+1]) };
                    rk[cp]  = r;                                  // 1/s
                    tkn[cp] = -(v2f){ta[2*cp], ta[2*cp+1]} * r;   // -t/s
                    wk[cp]  = (v2f){wa[2*cp], wa[2*cp+1]};        // w
                }
            }

#pragma unroll
            for (int j = 0; j < TB; ++j) {
                const float4 xv = *(const float4*)(xb + j * I_SZ + i); // ds_read_b128
                const float* xp = (const float*)&xv;
#pragma unroll
                for (int cp = 0; cp < 2; ++cp) {
                    const v2f x2 = { xp[2*cp], xp[2*cp+1] };
                    const v2f u  = __builtin_elementwise_fma(x2, rk[cp], tkn[cp]); // z
                    const v2f vq = u * u;                                          // z^2
                    const v2f vc = __builtin_elementwise_min(vq, (v2f)(12.0f));
                    const v2f xi = __builtin_elementwise_fma(vc, (v2f)(0.16666667f),
                                                             (v2f)(-1.0f));
                    v2f p = __builtin_elementwise_fma(xi, (v2f)(D6), (v2f)(D5));
                    p = __builtin_elementwise_fma(p, xi, (v2f)(D4));
                    p = __builtin_elementwise_fma(p, xi, (v2f)(D3));
                    p = __builtin_elementwise_fma(p, xi, (v2f)(D2));
                    p = __builtin_elementwise_fma(p, xi, (v2f)(D1));
                    p = __builtin_elementwise_fma(p, xi, (v2f)(D0));   // exp(-z^2/2)
                    const v2f y = u * wk[cp];                          // w*z
                    acc[j] = __builtin_elementwise_fma(-y, p, acc[j]); // += -w*z*e
                }
            }
        }

        // collapse pairs, reduce across the 32 i-split lanes
        float r[TB];
#pragma unroll
        for (int j = 0; j < TB; ++j) r[j] = acc[j].x + acc[j].y;
#pragma unroll
        for (int m = 1; m < SLN; m <<= 1)
#pragma unroll
            for (int j = 0; j < TB; ++j)
                r[j] += __shfl_xor(r[j], m, 64);

        if (sl < TB) {
            float v = 0.0f;
#pragma unroll
            for (int j = 0; j < TB; ++j)
                if (sl == j) v = r[j];
            Out[(size_t)(b0 + sl) * O_SZ + (obase + oi * 8)] = v;
        }
    }
}

extern "C" void kernel_launch(void* const* d_in, const int* in_sizes, int n_in,
                              void* d_out, int out_size, void* d_ws, size_t ws_size,
                              hipStream_t stream) {
    const float* x = (const float*)d_in[0];   // (B, I)
    const float* w = (const float*)d_in[1];   // (O, I)
    const float* s = (const float*)d_in[2];   // (O, I)
    const float* t = (const float*)d_in[3];   // (O, I)
    float* out = (float*)d_out;               // (B, O)

    dim3 grid(O_SZ / (8 * OITER), B_SZ / TB); // (32, 32) = 1024 blocks = 4/CU
    wavkan_dog_kernel<<<grid, 256, 0, stream>>>(x, w, s, t, out);
}

// Round 12
// 114.121 us; speedup vs baseline: 1.1781x; 1.1781x over previous
//
#include <hip/hip_runtime.h>

// x (B,I); w/s/t (O,I); out (B,O), all fp32.
#define B_SZ 256
#define O_SZ 1024
#define I_SZ 1024

#define TB   4     // b rows per block (LDS x tile) -- halved vs R10 for occupancy
#define SLN  32    // lanes per half splitting i
#define KITERS (I_SZ / (SLN * 4))   // 8
#define ISTEP  (SLN * 4)            // 128
#define OITER  4                    // o-groups per block (32 o's/block)

typedef float v2f __attribute__((ext_vector_type(2)));

// out[b,o] = sum_i w[o,i]*phi((x[b,i]-t[o,i])/s[o,i]),  phi(z) = -z*exp(-0.5 z^2)
// u = K*(x-t)/s, K = sqrt(0.5*log2 e) -> exp2(-u^2) = exp(-z^2/2);  w*z = u*(w/K)
// fma/mul packed (v_pk_*_f32); exp2 on trans pipe (v_exp_f32, ~16 cyc/wave).
//
// Busy model (validated R10: 2048 grp/SIMD x (4 pk x2 + 2 exp x16) = 82k ~ measured
// 80k cyc): trans pipe dominates busy; wall was busy/0.61. R11's poly-replace FAILED
// (VOP3P takes no literals -> scalarized, 127k busy) -- exp2 math restored.
// This round attacks the 39% idle with OCCUPANCY: TB=4 -> 16 KB LDS -> 8 blocks/CU
// = 8 waves/SIMD (VGPR ~36 fits the 64 cap of launch_bounds(256,8)).
// Spill history (R4/5/7/8): watch WRITE_SIZE ~1 MB as the no-spill signal.
__launch_bounds__(256, 8)
__global__ void wavkan_dog_kernel(const float* __restrict__ X,
                                  const float* __restrict__ W,
                                  const float* __restrict__ S,
                                  const float* __restrict__ T,
                                  float* __restrict__ Out) {
    const int tid  = threadIdx.x;
    const int wave = tid >> 6;
    const int lane = tid & 63;
    const int half = lane >> 5;
    const int sl   = lane & (SLN - 1);

    const int obase = blockIdx.x * (8 * OITER) + wave * 2 + half; // + oi*8
    const int b0    = blockIdx.y * TB;

    __shared__ __align__(16) float xls[TB * I_SZ];     // 16 KB

    const int r0 = obase * I_SZ + sl * 4;
    const float* wr = W + r0;
    const float* sr = S + r0;
    const float* tr = T + r0;

    // first w/s/t prefetch issued before the LDS fill (flies under the barrier)
    float4 sN = *(const float4*)(sr);
    float4 tN = *(const float4*)(tr);
    float4 wN = *(const float4*)(wr);

    {   // cooperative fill: x[b0:b0+4][:] is one contiguous 16 KB span
        const float4* Xg4 = (const float4*)(X + (size_t)b0 * I_SZ);
        float4* L4 = (float4*)xls;
#pragma unroll
        for (int p = 0; p < (TB * I_SZ / 4) / 256; ++p)
            L4[tid + p * 256] = Xg4[tid + p * 256];
    }
    __syncthreads();

    const float K  = 0.84932180028801904272f;  // sqrt(0.5 * log2 e)
    const float iK = 1.17741002251547469101f;  // 1/K
    const float* xb = xls + sl * 4;

#pragma unroll 1
    for (int oi = 0; oi < OITER; ++oi) {
        const int ob = oi * 8 * I_SZ;

        v2f acc[TB];
#pragma unroll
        for (int j = 0; j < TB; ++j) acc[j] = (v2f)(0.0f);

#pragma unroll 2
        for (int k = 0; k < KITERS; ++k) {
            const int i = k * ISTEP;
            const int in = (k < KITERS - 1) ? (ob + (k + 1) * ISTEP)
                                            : ((((oi + 1) & (OITER - 1)) * 8) * I_SZ);

            const float4 s4 = sN, t4 = tN, w4 = wN;
            sN = *(const float4*)(sr + in);     // prefetch next k (or next o-group)
            tN = *(const float4*)(tr + in);
            wN = *(const float4*)(wr + in);

            v2f rk[2], tkn[2], wk[2];
            {
                const float* sa = (const float*)&s4;
                const float* ta = (const float*)&t4;
                const float* wa = (const float*)&w4;
#pragma unroll
                for (int cp = 0; cp < 2; ++cp) {
                    const v2f r  = { __builtin_amdgcn_rcpf(sa[2*cp]),
                                     __builtin_amdgcn_rcpf(sa[2*cp+1]) };
                    const v2f tt = { ta[2*cp], ta[2*cp+1] };
                    const v2f ww = { wa[2*cp], wa[2*cp+1] };
                    rk[cp]  = r * K;
                    tkn[cp] = -(tt * rk[cp]);
                    wk[cp]  = ww * iK;
                }
            }

#pragma unroll
            for (int j = 0; j < TB; ++j) {
                const float4 xv = *(const float4*)(xb + j * I_SZ + i); // ds_read_b128
                const float* xp = (const float*)&xv;
#pragma unroll
                for (int cp = 0; cp < 2; ++cp) {
                    const v2f x2 = { xp[2*cp], xp[2*cp+1] };
                    const v2f u  = __builtin_elementwise_fma(x2, rk[cp], tkn[cp]); // z*K
                    const v2f m  = u * (-u);                                      // -(z*K)^2
                    v2f e;
                    e.x = __builtin_amdgcn_exp2f(m.x);                            // exp(-z^2/2)
                    e.y = __builtin_amdgcn_exp2f(m.y);
                    const v2f y = u * wk[cp];                                     // w*z
                    acc[j] = __builtin_elementwise_fma(-y, e, acc[j]);            // += -w*z*e
                }
            }
        }

        // collapse pairs, reduce across the 32 i-split lanes
        float r[TB];
#pragma unroll
        for (int j = 0; j < TB; ++j) r[j] = acc[j].x + acc[j].y;
#pragma unroll
        for (int m = 1; m < SLN; m <<= 1)
#pragma unroll
            for (int j = 0; j < TB; ++j)
                r[j] += __shfl_xor(r[j], m, 64);

        if (sl < TB) {
            float v = 0.0f;
#pragma unroll
            for (int j = 0; j < TB; ++j)
                if (sl == j) v = r[j];
            Out[(size_t)(b0 + sl) * O_SZ + (obase + oi * 8)] = v;
        }
    }
}

extern "C" void kernel_launch(void* const* d_in, const int* in_sizes, int n_in,
                              void* d_out, int out_size, void* d_ws, size_t ws_size,
                              hipStream_t stream) {
    const float* x = (const float*)d_in[0];   // (B, I)
    const float* w = (const float*)d_in[1];   // (O, I)
    const float* s = (const float*)d_in[2];   // (O, I)
    const float* t = (const float*)d_in[3];   // (O, I)
    float* out = (float*)d_out;               // (B, O)

    dim3 grid(O_SZ / (8 * OITER), B_SZ / TB); // (32, 64) = 2048 blocks = 8/CU resident
    wavkan_dog_kernel<<<grid, 256, 0, stream>>>(x, w, s, t, out);
}